// Round 18
// baseline (151.438 us; speedup 1.0000x reference)
//
#include <hip/hip_runtime.h>
#include <math.h>

#define Bn 128
#define Sn 200
#define NC3n 4000
#define GRUB Bn                 // 128 GRU blocks, 1 row each
#define FILLB (Bn * 4)          // 512 fill blocks, (b, quarter)

typedef float vf4 __attribute__((ext_vector_type(4)));

__device__ __forceinline__ float fexp(float x) { return __builtin_amdgcn_exp2f(x * 1.44269504f); }
__device__ __forceinline__ float frcp(float x) { return __builtin_amdgcn_rcpf(x); }
__device__ __forceinline__ float fsig(float x) { return frcp(1.f + fexp(-x)); }
__device__ __forceinline__ float rlanef(float v, int k) {
    return __int_as_float(__builtin_amdgcn_readlane(__float_as_int(v), k));
}
__device__ __forceinline__ void nt_store4(float* p, float4 q) {
    vf4 v; v.x = q.x; v.y = q.y; v.z = q.z; v.w = q.w;
    __builtin_nontemporal_store(v, (vf4*)p);
}

#define UPD(q, cbase) { int d = cc - (cbase); if ((unsigned)d < 4u) { \
    q.x = (d==0)?v:q.x; q.y = (d==1)?v:q.y; q.z = (d==2)?v:q.z; q.w = (d==3)?v:q.w; } }

struct GruLds {                 // ~69 KB
    float ring[2][16][64];      // out_h staging (8 KB)
    float pPart[Sn][68];        // per-lane mlp1 partials, padded rows (54.4 KB)
    float hbc[4][64];           // per-wave h broadcast strips
    float u[192], w0[192], w1[192];
    float hg[2][192];           // ping-pong W_hh@h + b_hh
    float gam[Sn];
    int   r[Sn];
};
struct FillLds {                // ~6.2 KB
    float gam[Sn], val[Sn];
    int   r[Sn], c3[Sn], succ[Sn], root[Sn];
    float A[64], Bv[64], C0[64], C1[64], W2[64];
    float l2b2;
};

__global__ __launch_bounds__(256, 2) void fused10_kernel(
    const int* __restrict__ c3_seq, const int* __restrict__ d_seq,
    const int* __restrict__ r_seq, const float* __restrict__ v_c3,
    const float* __restrict__ D_w, const float* __restrict__ v_d,
    const float* __restrict__ R_w, const float* __restrict__ W_ih,
    const float* __restrict__ W_hh, const float* __restrict__ b_ih,
    const float* __restrict__ b_hh,
    const float* __restrict__ l1_w1, const float* __restrict__ l1_b1,
    const float* __restrict__ l1_w2, const float* __restrict__ l1_b2,
    const float* __restrict__ l2_w1, const float* __restrict__ l2_b1,
    const float* __restrict__ l2_w2, const float* __restrict__ l2_b2,
    float* __restrict__ out_alpha, float* __restrict__ out_h,
    float* __restrict__ out_c3)
{
    __shared__ __align__(16) union { GruLds g; FillLds f; } S;

    const int tid = threadIdx.x;
    const int bid = blockIdx.x;

    if (bid < GRUB) {
        // ===== GRU + mlp1 + alpha: 1 row, 4 role waves, 1 barrier/step.
        // Micro-pass: hg reads issued FIRST after barrier; gam/r prefetched;
        // role-3 side work rebalanced so waves arrive at barrier together. =====
        __builtin_amdgcn_s_setprio(1);
        const int b    = bid;
        const int role = tid >> 6;          // 0=r,1=z,2=n,3=mlp1
        const int j    = tid & 63;

        if (tid < Sn) {
            S.g.gam[tid] = D_w[d_seq[b * Sn + tid]];
            S.g.r[tid]   = r_seq[b * Sn + tid];
        }
        // fold xg: u = W_ih[rho,:64]@v_d ; w0/w1 = W_ih[rho,64:]@R_w[r] + b_ih[rho]
        if (tid < 192) {
            const float4* rp  = (const float4*)(W_ih + (size_t)tid * 128);
            const float4* vd4 = (const float4*)v_d;
            const float4* q04 = (const float4*)R_w;
            const float4* q14 = (const float4*)(R_w + 64);
            float u = 0.f, w0 = 0.f, w1 = 0.f;
            #pragma unroll 4
            for (int k = 0; k < 16; ++k) {
                float4 a  = rp[k];
                float4 bb = rp[16 + k];
                float4 vd = vd4[k], q0 = q04[k], q1 = q14[k];
                u  += a.x*vd.x + a.y*vd.y + a.z*vd.z + a.w*vd.w;
                w0 += bb.x*q0.x + bb.y*q0.y + bb.z*q0.z + bb.w*q0.w;
                w1 += bb.x*q1.x + bb.y*q1.y + bb.z*q1.z + bb.w*q1.w;
            }
            float bih = b_ih[tid];
            S.g.u[tid]  = u;
            S.g.w0[tid] = w0 + bih;
            S.g.w1[tid] = w1 + bih;
        }
        // per-wave weight row: role<3 -> W_hh row role*64+j ; role==3 -> l1_w1 row j
        float w[64];
        {
            const float* src = (role < 3) ? (W_hh + (size_t)(role * 64 + j) * 64)
                                          : (l1_w1 + (size_t)j * 64);
            const float4* s4 = (const float4*)src;
            #pragma unroll
            for (int k = 0; k < 16; ++k) {
                float4 v = s4[k];
                w[4*k+0]=v.x; w[4*k+1]=v.y; w[4*k+2]=v.z; w[4*k+3]=v.w;
            }
        }
        // keep the weights live in VGPRs across the loop (no remat/sink)
        #pragma unroll
        for (int k = 0; k < 16; ++k)
            asm volatile("" : "+v"(w[4*k+0]), "+v"(w[4*k+1]), "+v"(w[4*k+2]), "+v"(w[4*k+3]));

        float bown = 0.f, l1b = 0.f, l1w2v = 0.f;
        if (role < 3) {
            bown = b_hh[role * 64 + j];
            S.g.hg[0][role * 64 + j] = bown;    // h0=0 -> hg(t=0)=b_hh
        } else {
            l1b = l1_b1[j]; l1w2v = l1_w2[j];
        }
        const float l1b2c = l1_b2[0];
        __syncthreads();                        // prologue barrier

        const float uj  = S.g.u[j],  u1  = S.g.u[64+j],  u2  = S.g.u[128+j];
        const float w00 = S.g.w0[j], w01 = S.g.w0[64+j], w02 = S.g.w0[128+j];
        const float w10 = S.g.w1[j], w11 = S.g.w1[64+j], w12 = S.g.w1[128+j];

        float vh = 0.f;
        float* outh_base = out_h + (size_t)b * Sn * 64;
        const int rloc = 4 * role + (j >> 4);
        const int cloc = (j & 15) * 4;
        float gamc = S.g.gam[0];                // prefetched step inputs
        int   rc   = S.g.r[0];

        for (int t = 0; t < Sn; ++t) {
            const int buf = t & 1;
            // (1) CRITICAL dependency first: issue the 3 hg reads immediately
            float hr = S.g.hg[buf][j], hz = S.g.hg[buf][64+j], hn = S.g.hg[buf][128+j];
            // flush moved after: its ring-read + global-store hide under gates
            if (t && (t & 15) == 0) {
                const int hb = ((t >> 4) & 1) ^ 1;
                float4 v4 = *(const float4*)&S.g.ring[hb][rloc][cloc];
                *(float4*)(outh_base + (size_t)(t - 16 + rloc) * 64 + cloc) = v4;
            }
            float gam = gamc;
            int   r   = rc;
            float rg = fsig(fmaf(gam, uj, r ? w10 : w00) + hr);
            float zg = fsig(fmaf(gam, u1, r ? w11 : w01) + hz);
            float e2 = fexp(2.f * (fmaf(gam, u2, r ? w12 : w02) + rg * hn));
            float ng = 1.f - 2.f * frcp(e2 + 1.f);   // tanh
            vh = (1.f - zg) * ng + zg * vh;
            // self-broadcast h: write strip, BATCH all 16 b128 reads (single wait)
            S.g.hbc[role][j] = vh;
            // (3) role-3 side work needing only vh issues here (arrival balance)
            if (role == 3) S.g.ring[(t >> 4) & 1][t & 15][j] = vh;
            float4 hreg[16];
            #pragma unroll
            for (int k = 0; k < 16; ++k)
                hreg[k] = *(const float4*)&S.g.hbc[role][k * 4];
            __builtin_amdgcn_sched_barrier(0);  // keep loads batched above the fmas
            // (2) prefetch next-step gam/r under the fma block
            if (t + 1 < Sn) { gamc = S.g.gam[t + 1]; rc = S.g.r[t + 1]; }
            float a0=0.f, a1=0.f, a2=0.f, a3=0.f;
            #pragma unroll
            for (int k = 0; k < 16; ++k) {
                a0 = fmaf(w[4*k+0], hreg[k].x, a0);
                a1 = fmaf(w[4*k+1], hreg[k].y, a1);
                a2 = fmaf(w[4*k+2], hreg[k].z, a2);
                a3 = fmaf(w[4*k+3], hreg[k].w, a3);
            }
            float dot = (a0 + a1) + (a2 + a3);
            if (role < 3) {
                S.g.hg[buf ^ 1][role * 64 + j] = bown + dot;
            } else {
                S.g.pPart[t][j] = fmaxf(dot + l1b, 0.f) * l1w2v;   // raw partial
            }
            __syncthreads();
        }
        if (role < 2) {                         // rows 192..199 from ring[0][0..7]
            float4 v4 = *(const float4*)&S.g.ring[0][rloc][cloc];
            *(float4*)(outh_base + (size_t)(192 + rloc) * 64 + cloc) = v4;
        }
        // deferred mlp1 sums + alpha chain (role 3)
        if (role == 3) {
            const int j3 = (j < 8) ? (192 + j) : 199;
            float4 s0 = make_float4(0.f,0.f,0.f,0.f), s1 = s0, s2 = s0, s3 = s0;
            const float4* p0 = (const float4*)&S.g.pPart[j][0];
            const float4* p1 = (const float4*)&S.g.pPart[64 + j][0];
            const float4* p2 = (const float4*)&S.g.pPart[128 + j][0];
            const float4* p3 = (const float4*)&S.g.pPart[j3][0];
            #pragma unroll
            for (int k = 0; k < 16; ++k) {
                float4 a = p0[k], bq = p1[k], c = p2[k], d = p3[k];
                s0.x += a.x;  s0.y += a.y;  s0.z += a.z;  s0.w += a.w;
                s1.x += bq.x; s1.y += bq.y; s1.z += bq.z; s1.w += bq.w;
                s2.x += c.x;  s2.y += c.y;  s2.z += c.z;  s2.w += c.w;
                s3.x += d.x;  s3.y += d.y;  s3.z += d.z;  s3.w += d.w;
            }
            float an0 = ((s0.x+s0.y)+(s0.z+s0.w)) + l1b2c;
            float an1 = ((s1.x+s1.y)+(s1.z+s1.w)) + l1b2c;
            float an2 = ((s2.x+s2.y)+(s2.z+s2.w)) + l1b2c;
            float an3 = ((s3.x+s3.y)+(s3.z+s3.w)) + l1b2c;
            float g0 = S.g.gam[j],       g1 = S.g.gam[64 + j];
            float g2 = S.g.gam[128 + j], g3 = S.g.gam[j3];
            int   r0 = S.g.r[j],         r1 = S.g.r[64 + j];
            int   r2 = S.g.r[128 + j],   r3 = S.g.r[j3];
            float alpha = 0.f;
            float* oa = out_alpha + b * Sn;
            for (int t = 0; t < Sn; ++t) {
                const int q = t >> 6, l = t & 63;
                float an, g; int rr;
                if (q == 0)      { an = rlanef(an0,l); g = rlanef(g0,l); rr = __builtin_amdgcn_readlane(r0,l); }
                else if (q == 1) { an = rlanef(an1,l); g = rlanef(g1,l); rr = __builtin_amdgcn_readlane(r1,l); }
                else if (q == 2) { an = rlanef(an2,l); g = rlanef(g2,l); rr = __builtin_amdgcn_readlane(r2,l); }
                else             { an = rlanef(an3,l); g = rlanef(g3,l); rr = __builtin_amdgcn_readlane(r3,l); }
                bool cond = (alpha - g) >= 0.f;
                alpha = rr ? (cond ? an : alpha) : (cond ? alpha : an);
                if (j == 0) oa[t] = alpha;
            }
        }
    } else {
        // ===== C3 chain + contiguous forward-fill: one (row, quarter) =====
        const int fb = bid - GRUB;
        const int b  = fb >> 2;
        const int qt = fb & 3;
        if (tid < Sn) {
            S.f.gam[tid] = D_w[d_seq[b*Sn + tid]];
            S.f.r[tid]   = r_seq[b*Sn + tid];
            S.f.c3[tid]  = c3_seq[b*Sn + tid];
        }
        if (tid < 64) {
            const float4* row4 = (const float4*)(l2_w1 + (size_t)tid * 192);
            const float4* vc4  = (const float4*)v_c3;
            const float4* vd4  = (const float4*)v_d;
            const float4* q04  = (const float4*)R_w;
            const float4* q14  = (const float4*)(R_w + 64);
            float a2=0.f, b2=0.f, c0=0.f, c1=0.f;
            #pragma unroll 4
            for (int k = 0; k < 16; ++k) {
                float4 ra = row4[k], rb = row4[16+k], rc = row4[32+k];
                float4 vc = vc4[k], vd = vd4[k], q0 = q04[k], q1 = q14[k];
                a2 += ra.x*vc.x + ra.y*vc.y + ra.z*vc.z + ra.w*vc.w;
                b2 += rb.x*vd.x + rb.y*vd.y + rb.z*vd.z + rb.w*vd.w;
                c0 += rc.x*q0.x + rc.y*q0.y + rc.z*q0.z + rc.w*q0.w;
                c1 += rc.x*q1.x + rc.y*q1.y + rc.z*q1.z + rc.w*q1.w;
            }
            S.f.A[tid]  = a2;
            S.f.Bv[tid] = b2;
            S.f.C0[tid] = c0 + l2_b1[tid];
            S.f.C1[tid] = c1 + l2_b1[tid];
            S.f.W2[tid] = l2_w2[tid];
        }
        if (tid == 0) S.f.l2b2 = l2_b2[0];
        __syncthreads();
        if (tid < Sn) {
            int c = S.f.c3[tid];
            int s = -1;
            for (int u = tid + 1; u < Sn; ++u)
                if (S.f.c3[u] == c) { s = u; break; }
            S.f.succ[tid] = s;
            int rt = 1;
            for (int u = 0; u < tid; ++u)
                if (S.f.c3[u] == c) { rt = 0; break; }
            S.f.root[tid] = rt;
        }
        __syncthreads();
        {   // chain walk, 16-lane groups
            const int g  = tid >> 4;
            const int l  = tid & 15;
            const int j0 = l * 4;
            float A0=S.f.A[j0],  A1=S.f.A[j0+1],  A2=S.f.A[j0+2],  A3=S.f.A[j0+3];
            float B0=S.f.Bv[j0], B1=S.f.Bv[j0+1], B2=S.f.Bv[j0+2], B3=S.f.Bv[j0+3];
            float C00=S.f.C0[j0],C01=S.f.C0[j0+1],C02=S.f.C0[j0+2],C03=S.f.C0[j0+3];
            float C10=S.f.C1[j0],C11=S.f.C1[j0+1],C12=S.f.C1[j0+2],C13=S.f.C1[j0+3];
            float W0=S.f.W2[j0], W1=S.f.W2[j0+1], W2v=S.f.W2[j0+2],W3=S.f.W2[j0+3];
            float l2b2 = S.f.l2b2;
            for (int t0 = g; t0 < Sn; t0 += 16) {
                if (!S.f.root[t0]) continue;
                float beta = 0.f;
                int t = t0;
                while (t >= 0) {
                    float gam = S.f.gam[t];
                    int   r   = S.f.r[t];
                    float s = W0*fmaxf(A0*beta + B0*gam + (r ? C10 : C00), 0.f)
                            + W1*fmaxf(A1*beta + B1*gam + (r ? C11 : C01), 0.f)
                            + W2v*fmaxf(A2*beta + B2*gam + (r ? C12 : C02), 0.f)
                            + W3*fmaxf(A3*beta + B3*gam + (r ? C13 : C03), 0.f);
                    s += __shfl_xor(s, 1, 16);
                    s += __shfl_xor(s, 2, 16);
                    s += __shfl_xor(s, 4, 16);
                    s += __shfl_xor(s, 8, 16);
                    beta = s + l2b2;
                    if (l == 0) S.f.val[t] = beta;
                    t = S.f.succ[t];
                }
            }
        }
        __syncthreads();
        // forward-fill 50 rows x 16KB, contiguous per-block stream (nontemporal)
        const int cA = tid*4, cB = 1024 + tid*4, cC = 2048 + tid*4, cD = 3072 + tid*4;
        float4 qA = make_float4(0.f,0.f,0.f,0.f), qB = qA, qC = qA, qD = qA;
        const int t0 = qt * 50;
        for (int t = 0; t < t0; ++t) {          // pre-scan (no stores)
            int cc = S.f.c3[t]; float v = S.f.val[t];
            UPD(qA, cA) UPD(qB, cB) UPD(qC, cC) UPD(qD, cD)
        }
        float* rowp = out_c3 + (size_t)b * Sn * NC3n + (size_t)t0 * NC3n;
        const bool doD = (tid < 232);
        for (int t = t0; t < t0 + 50; ++t) {
            int cc = S.f.c3[t]; float v = S.f.val[t];
            UPD(qA, cA) UPD(qB, cB) UPD(qC, cC) UPD(qD, cD)
            nt_store4(rowp + cA, qA);
            nt_store4(rowp + cB, qB);
            nt_store4(rowp + cC, qC);
            if (doD) nt_store4(rowp + cD, qD);
            rowp += NC3n;
        }
    }
}

extern "C" void kernel_launch(void* const* d_in, const int* in_sizes, int n_in,
                              void* d_out, int out_size, void* d_ws, size_t ws_size,
                              hipStream_t stream)
{
    const int*   c3_seq = (const int*)  d_in[0];
    const int*   d_seq  = (const int*)  d_in[1];
    const int*   r_seq  = (const int*)  d_in[2];
    const float* v_c3   = (const float*)d_in[3];
    const float* D_w    = (const float*)d_in[4];
    const float* v_d    = (const float*)d_in[5];
    const float* R_w    = (const float*)d_in[6];
    const float* W_ih   = (const float*)d_in[7];
    const float* W_hh   = (const float*)d_in[8];
    const float* b_ih   = (const float*)d_in[9];
    const float* b_hh   = (const float*)d_in[10];
    const float* l1_w1  = (const float*)d_in[11];
    const float* l1_b1  = (const float*)d_in[12];
    const float* l1_w2  = (const float*)d_in[13];
    const float* l1_b2  = (const float*)d_in[14];
    const float* l2_w1  = (const float*)d_in[15];
    const float* l2_b1  = (const float*)d_in[16];
    const float* l2_w2  = (const float*)d_in[17];
    const float* l2_b2  = (const float*)d_in[18];

    float* out_alpha = (float*)d_out;
    float* out_h     = out_alpha + Bn*Sn;
    float* out_c3    = out_h + (size_t)Bn*Sn*64;

    fused10_kernel<<<GRUB + FILLB, 256, 0, stream>>>(
        c3_seq, d_seq, r_seq, v_c3, D_w, v_d, R_w, W_ih, W_hh, b_ih, b_hh,
        l1_w1, l1_b1, l1_w2, l1_b2, l2_w1, l2_b1, l2_w2, l2_b2,
        out_alpha, out_h, out_c3);
}

// Round 19
// 151.390 us; speedup vs baseline: 1.0003x; 1.0003x over previous
//
#include <hip/hip_runtime.h>
#include <math.h>

#define Bn 128
#define Sn 200
#define NC3n 4000
#define GRUB Bn                 // 128 GRU blocks, 1 row each
#define FILLB (Bn * 4)          // 512 fill blocks, (b, quarter)

typedef float vf4 __attribute__((ext_vector_type(4)));

__device__ __forceinline__ float fexp(float x) { return __builtin_amdgcn_exp2f(x * 1.44269504f); }
__device__ __forceinline__ float frcp(float x) { return __builtin_amdgcn_rcpf(x); }
__device__ __forceinline__ float fsig(float x) { return frcp(1.f + fexp(-x)); }
__device__ __forceinline__ float rlanef(float v, int k) {
    return __int_as_float(__builtin_amdgcn_readlane(__float_as_int(v), k));
}
__device__ __forceinline__ void nt_store4(float* p, float4 q) {
    vf4 v; v.x = q.x; v.y = q.y; v.z = q.z; v.w = q.w;
    __builtin_nontemporal_store(v, (vf4*)p);
}
// LDS-only barrier: global stores stay in flight (validated R12); the per-step
// direct out_h store below is therefore free (drained only at kernel end).
__device__ __forceinline__ void lds_barrier() {
    __builtin_amdgcn_sched_barrier(0);
    asm volatile("s_waitcnt lgkmcnt(0)" ::: "memory");
    __builtin_amdgcn_s_barrier();
    __builtin_amdgcn_sched_barrier(0);
}

#define UPD(q, cbase) { int d = cc - (cbase); if ((unsigned)d < 4u) { \
    q.x = (d==0)?v:q.x; q.y = (d==1)?v:q.y; q.z = (d==2)?v:q.z; q.w = (d==3)?v:q.w; } }

struct GruLds {                 // ~61 KB (ring removed)
    float pPart[Sn][68];        // per-lane mlp1 partials, padded rows (54.4 KB)
    float hbc[4][64];           // per-wave h broadcast strips
    float u[192], w0[192], w1[192];
    float hg[2][192];           // ping-pong W_hh@h + b_hh
    float gam[Sn];
    int   r[Sn];
};
struct FillLds {                // ~6.2 KB
    float gam[Sn], val[Sn];
    int   r[Sn], c3[Sn], succ[Sn], root[Sn];
    float A[64], Bv[64], C0[64], C1[64], W2[64];
    float l2b2;
};

__global__ __launch_bounds__(256, 2) void fused11_kernel(
    const int* __restrict__ c3_seq, const int* __restrict__ d_seq,
    const int* __restrict__ r_seq, const float* __restrict__ v_c3,
    const float* __restrict__ D_w, const float* __restrict__ v_d,
    const float* __restrict__ R_w, const float* __restrict__ W_ih,
    const float* __restrict__ W_hh, const float* __restrict__ b_ih,
    const float* __restrict__ b_hh,
    const float* __restrict__ l1_w1, const float* __restrict__ l1_b1,
    const float* __restrict__ l1_w2, const float* __restrict__ l1_b2,
    const float* __restrict__ l2_w1, const float* __restrict__ l2_b1,
    const float* __restrict__ l2_w2, const float* __restrict__ l2_b2,
    float* __restrict__ out_alpha, float* __restrict__ out_h,
    float* __restrict__ out_c3)
{
    __shared__ __align__(16) union { GruLds g; FillLds f; } S;

    const int tid = threadIdx.x;
    const int bid = blockIdx.x;

    if (bid < GRUB) {
        // ===== GRU + mlp1 + alpha: 1 row, 4 role waves, 1 LDS-only barrier/step,
        // no in-loop cross-lane ops, direct out_h stores (no ring) =====
        __builtin_amdgcn_s_setprio(1);
        const int b    = bid;
        const int role = tid >> 6;          // 0=r,1=z,2=n,3=mlp1
        const int j    = tid & 63;

        if (tid < Sn) {
            S.g.gam[tid] = D_w[d_seq[b * Sn + tid]];
            S.g.r[tid]   = r_seq[b * Sn + tid];
        }
        // fold xg: u = W_ih[rho,:64]@v_d ; w0/w1 = W_ih[rho,64:]@R_w[r] + b_ih[rho]
        if (tid < 192) {
            const float4* rp  = (const float4*)(W_ih + (size_t)tid * 128);
            const float4* vd4 = (const float4*)v_d;
            const float4* q04 = (const float4*)R_w;
            const float4* q14 = (const float4*)(R_w + 64);
            float u = 0.f, w0 = 0.f, w1 = 0.f;
            #pragma unroll 4
            for (int k = 0; k < 16; ++k) {
                float4 a  = rp[k];
                float4 bb = rp[16 + k];
                float4 vd = vd4[k], q0 = q04[k], q1 = q14[k];
                u  += a.x*vd.x + a.y*vd.y + a.z*vd.z + a.w*vd.w;
                w0 += bb.x*q0.x + bb.y*q0.y + bb.z*q0.z + bb.w*q0.w;
                w1 += bb.x*q1.x + bb.y*q1.y + bb.z*q1.z + bb.w*q1.w;
            }
            float bih = b_ih[tid];
            S.g.u[tid]  = u;
            S.g.w0[tid] = w0 + bih;
            S.g.w1[tid] = w1 + bih;
        }
        // per-wave weight row: role<3 -> W_hh row role*64+j ; role==3 -> l1_w1 row j
        float w[64];
        {
            const float* src = (role < 3) ? (W_hh + (size_t)(role * 64 + j) * 64)
                                          : (l1_w1 + (size_t)j * 64);
            const float4* s4 = (const float4*)src;
            #pragma unroll
            for (int k = 0; k < 16; ++k) {
                float4 v = s4[k];
                w[4*k+0]=v.x; w[4*k+1]=v.y; w[4*k+2]=v.z; w[4*k+3]=v.w;
            }
        }
        // keep the weights live in VGPRs across the loop (no remat/sink)
        #pragma unroll
        for (int k = 0; k < 16; ++k)
            asm volatile("" : "+v"(w[4*k+0]), "+v"(w[4*k+1]), "+v"(w[4*k+2]), "+v"(w[4*k+3]));

        float bown = 0.f, l1b = 0.f, l1w2v = 0.f;
        if (role < 3) {
            bown = b_hh[role * 64 + j];
            S.g.hg[0][role * 64 + j] = bown;    // h0=0 -> hg(t=0)=b_hh
        } else {
            l1b = l1_b1[j]; l1w2v = l1_w2[j];
        }
        const float l1b2c = l1_b2[0];
        __syncthreads();                        // prologue barrier

        const float uj  = S.g.u[j],  u1  = S.g.u[64+j],  u2  = S.g.u[128+j];
        const float w00 = S.g.w0[j], w01 = S.g.w0[64+j], w02 = S.g.w0[128+j];
        const float w10 = S.g.w1[j], w11 = S.g.w1[64+j], w12 = S.g.w1[128+j];

        float vh = 0.f;
        float* outp = out_h + (size_t)b * Sn * 64 + j;   // role-3 direct stores
        float gamc = S.g.gam[0];                // prefetched step inputs
        int   rc   = S.g.r[0];

        for (int t = 0; t < Sn; ++t) {
            const int buf = t & 1;
            // critical dependency first: the 3 hg reads
            float hr = S.g.hg[buf][j], hz = S.g.hg[buf][64+j], hn = S.g.hg[buf][128+j];
            float gam = gamc;
            int   r   = rc;
            float rg = fsig(fmaf(gam, uj, r ? w10 : w00) + hr);
            float zg = fsig(fmaf(gam, u1, r ? w11 : w01) + hz);
            float e2 = fexp(2.f * (fmaf(gam, u2, r ? w12 : w02) + rg * hn));
            float ng = 1.f - 2.f * frcp(e2 + 1.f);   // tanh
            vh = (1.f - zg) * ng + zg * vh;
            // self-broadcast h: write strip, BATCH all 16 b128 reads (single wait)
            S.g.hbc[role][j] = vh;
            if (role == 3) { outp[0] = vh; outp += 64; }   // fire-and-forget store
            float4 hreg[16];
            #pragma unroll
            for (int k = 0; k < 16; ++k)
                hreg[k] = *(const float4*)&S.g.hbc[role][k * 4];
            __builtin_amdgcn_sched_barrier(0);  // keep loads batched above the fmas
            if (t + 1 < Sn) { gamc = S.g.gam[t + 1]; rc = S.g.r[t + 1]; }
            float a0=0.f, a1=0.f, a2=0.f, a3=0.f;
            #pragma unroll
            for (int k = 0; k < 16; ++k) {
                a0 = fmaf(w[4*k+0], hreg[k].x, a0);
                a1 = fmaf(w[4*k+1], hreg[k].y, a1);
                a2 = fmaf(w[4*k+2], hreg[k].z, a2);
                a3 = fmaf(w[4*k+3], hreg[k].w, a3);
            }
            float dot = (a0 + a1) + (a2 + a3);
            if (role < 3) {
                S.g.hg[buf ^ 1][role * 64 + j] = bown + dot;
            } else {
                S.g.pPart[t][j] = fmaxf(dot + l1b, 0.f) * l1w2v;   // raw partial
            }
            lds_barrier();                      // LDS-only: stores stay in flight
        }
        // deferred mlp1 sums + alpha chain (role 3)
        if (role == 3) {
            const int j3 = (j < 8) ? (192 + j) : 199;
            float4 s0 = make_float4(0.f,0.f,0.f,0.f), s1 = s0, s2 = s0, s3 = s0;
            const float4* p0 = (const float4*)&S.g.pPart[j][0];
            const float4* p1 = (const float4*)&S.g.pPart[64 + j][0];
            const float4* p2 = (const float4*)&S.g.pPart[128 + j][0];
            const float4* p3 = (const float4*)&S.g.pPart[j3][0];
            #pragma unroll
            for (int k = 0; k < 16; ++k) {
                float4 a = p0[k], bq = p1[k], c = p2[k], d = p3[k];
                s0.x += a.x;  s0.y += a.y;  s0.z += a.z;  s0.w += a.w;
                s1.x += bq.x; s1.y += bq.y; s1.z += bq.z; s1.w += bq.w;
                s2.x += c.x;  s2.y += c.y;  s2.z += c.z;  s2.w += c.w;
                s3.x += d.x;  s3.y += d.y;  s3.z += d.z;  s3.w += d.w;
            }
            float an0 = ((s0.x+s0.y)+(s0.z+s0.w)) + l1b2c;
            float an1 = ((s1.x+s1.y)+(s1.z+s1.w)) + l1b2c;
            float an2 = ((s2.x+s2.y)+(s2.z+s2.w)) + l1b2c;
            float an3 = ((s3.x+s3.y)+(s3.z+s3.w)) + l1b2c;
            float g0 = S.g.gam[j],       g1 = S.g.gam[64 + j];
            float g2 = S.g.gam[128 + j], g3 = S.g.gam[j3];
            int   r0 = S.g.r[j],         r1 = S.g.r[64 + j];
            int   r2 = S.g.r[128 + j],   r3 = S.g.r[j3];
            float alpha = 0.f;
            float* oa = out_alpha + b * Sn;
            for (int t = 0; t < Sn; ++t) {
                const int q = t >> 6, l = t & 63;
                float an, g; int rr;
                if (q == 0)      { an = rlanef(an0,l); g = rlanef(g0,l); rr = __builtin_amdgcn_readlane(r0,l); }
                else if (q == 1) { an = rlanef(an1,l); g = rlanef(g1,l); rr = __builtin_amdgcn_readlane(r1,l); }
                else if (q == 2) { an = rlanef(an2,l); g = rlanef(g2,l); rr = __builtin_amdgcn_readlane(r2,l); }
                else             { an = rlanef(an3,l); g = rlanef(g3,l); rr = __builtin_amdgcn_readlane(r3,l); }
                bool cond = (alpha - g) >= 0.f;
                alpha = rr ? (cond ? an : alpha) : (cond ? alpha : an);
                if (j == 0) oa[t] = alpha;
            }
        }
    } else {
        // ===== C3 chain + contiguous forward-fill: one (row, quarter) =====
        const int fb = bid - GRUB;
        const int b  = fb >> 2;
        const int qt = fb & 3;
        if (tid < Sn) {
            S.f.gam[tid] = D_w[d_seq[b*Sn + tid]];
            S.f.r[tid]   = r_seq[b*Sn + tid];
            S.f.c3[tid]  = c3_seq[b*Sn + tid];
        }
        if (tid < 64) {
            const float4* row4 = (const float4*)(l2_w1 + (size_t)tid * 192);
            const float4* vc4  = (const float4*)v_c3;
            const float4* vd4  = (const float4*)v_d;
            const float4* q04  = (const float4*)R_w;
            const float4* q14  = (const float4*)(R_w + 64);
            float a2=0.f, b2=0.f, c0=0.f, c1=0.f;
            #pragma unroll 4
            for (int k = 0; k < 16; ++k) {
                float4 ra = row4[k], rb = row4[16+k], rc = row4[32+k];
                float4 vc = vc4[k], vd = vd4[k], q0 = q04[k], q1 = q14[k];
                a2 += ra.x*vc.x + ra.y*vc.y + ra.z*vc.z + ra.w*vc.w;
                b2 += rb.x*vd.x + rb.y*vd.y + rb.z*vd.z + rb.w*vd.w;
                c0 += rc.x*q0.x + rc.y*q0.y + rc.z*q0.z + rc.w*q0.w;
                c1 += rc.x*q1.x + rc.y*q1.y + rc.z*q1.z + rc.w*q1.w;
            }
            S.f.A[tid]  = a2;
            S.f.Bv[tid] = b2;
            S.f.C0[tid] = c0 + l2_b1[tid];
            S.f.C1[tid] = c1 + l2_b1[tid];
            S.f.W2[tid] = l2_w2[tid];
        }
        if (tid == 0) S.f.l2b2 = l2_b2[0];
        __syncthreads();
        if (tid < Sn) {
            int c = S.f.c3[tid];
            int s = -1;
            for (int u = tid + 1; u < Sn; ++u)
                if (S.f.c3[u] == c) { s = u; break; }
            S.f.succ[tid] = s;
            int rt = 1;
            for (int u = 0; u < tid; ++u)
                if (S.f.c3[u] == c) { rt = 0; break; }
            S.f.root[tid] = rt;
        }
        __syncthreads();
        {   // chain walk, 16-lane groups
            const int g  = tid >> 4;
            const int l  = tid & 15;
            const int j0 = l * 4;
            float A0=S.f.A[j0],  A1=S.f.A[j0+1],  A2=S.f.A[j0+2],  A3=S.f.A[j0+3];
            float B0=S.f.Bv[j0], B1=S.f.Bv[j0+1], B2=S.f.Bv[j0+2], B3=S.f.Bv[j0+3];
            float C00=S.f.C0[j0],C01=S.f.C0[j0+1],C02=S.f.C0[j0+2],C03=S.f.C0[j0+3];
            float C10=S.f.C1[j0],C11=S.f.C1[j0+1],C12=S.f.C1[j0+2],C13=S.f.C1[j0+3];
            float W0=S.f.W2[j0], W1=S.f.W2[j0+1], W2v=S.f.W2[j0+2],W3=S.f.W2[j0+3];
            float l2b2 = S.f.l2b2;
            for (int t0 = g; t0 < Sn; t0 += 16) {
                if (!S.f.root[t0]) continue;
                float beta = 0.f;
                int t = t0;
                while (t >= 0) {
                    float gam = S.f.gam[t];
                    int   r   = S.f.r[t];
                    float s = W0*fmaxf(A0*beta + B0*gam + (r ? C10 : C00), 0.f)
                            + W1*fmaxf(A1*beta + B1*gam + (r ? C11 : C01), 0.f)
                            + W2v*fmaxf(A2*beta + B2*gam + (r ? C12 : C02), 0.f)
                            + W3*fmaxf(A3*beta + B3*gam + (r ? C13 : C03), 0.f);
                    s += __shfl_xor(s, 1, 16);
                    s += __shfl_xor(s, 2, 16);
                    s += __shfl_xor(s, 4, 16);
                    s += __shfl_xor(s, 8, 16);
                    beta = s + l2b2;
                    if (l == 0) S.f.val[t] = beta;
                    t = S.f.succ[t];
                }
            }
        }
        __syncthreads();
        // forward-fill 50 rows x 16KB, contiguous per-block stream (nontemporal)
        const int cA = tid*4, cB = 1024 + tid*4, cC = 2048 + tid*4, cD = 3072 + tid*4;
        float4 qA = make_float4(0.f,0.f,0.f,0.f), qB = qA, qC = qA, qD = qA;
        const int t0 = qt * 50;
        for (int t = 0; t < t0; ++t) {          // pre-scan (no stores)
            int cc = S.f.c3[t]; float v = S.f.val[t];
            UPD(qA, cA) UPD(qB, cB) UPD(qC, cC) UPD(qD, cD)
        }
        float* rowp = out_c3 + (size_t)b * Sn * NC3n + (size_t)t0 * NC3n;
        const bool doD = (tid < 232);
        for (int t = t0; t < t0 + 50; ++t) {
            int cc = S.f.c3[t]; float v = S.f.val[t];
            UPD(qA, cA) UPD(qB, cB) UPD(qC, cC) UPD(qD, cD)
            nt_store4(rowp + cA, qA);
            nt_store4(rowp + cB, qB);
            nt_store4(rowp + cC, qC);
            if (doD) nt_store4(rowp + cD, qD);
            rowp += NC3n;
        }
    }
}

extern "C" void kernel_launch(void* const* d_in, const int* in_sizes, int n_in,
                              void* d_out, int out_size, void* d_ws, size_t ws_size,
                              hipStream_t stream)
{
    const int*   c3_seq = (const int*)  d_in[0];
    const int*   d_seq  = (const int*)  d_in[1];
    const int*   r_seq  = (const int*)  d_in[2];
    const float* v_c3   = (const float*)d_in[3];
    const float* D_w    = (const float*)d_in[4];
    const float* v_d    = (const float*)d_in[5];
    const float* R_w    = (const float*)d_in[6];
    const float* W_ih   = (const float*)d_in[7];
    const float* W_hh   = (const float*)d_in[8];
    const float* b_ih   = (const float*)d_in[9];
    const float* b_hh   = (const float*)d_in[10];
    const float* l1_w1  = (const float*)d_in[11];
    const float* l1_b1  = (const float*)d_in[12];
    const float* l1_w2  = (const float*)d_in[13];
    const float* l1_b2  = (const float*)d_in[14];
    const float* l2_w1  = (const float*)d_in[15];
    const float* l2_b1  = (const float*)d_in[16];
    const float* l2_w2  = (const float*)d_in[17];
    const float* l2_b2  = (const float*)d_in[18];

    float* out_alpha = (float*)d_out;
    float* out_h     = out_alpha + Bn*Sn;
    float* out_c3    = out_h + (size_t)Bn*Sn*64;

    fused11_kernel<<<GRUB + FILLB, 256, 0, stream>>>(
        c3_seq, d_seq, r_seq, v_c3, D_w, v_d, R_w, W_ih, W_hh, b_ih, b_hh,
        l1_w1, l1_b1, l1_w2, l1_b2, l2_w1, l2_b1, l2_w2, l2_b2,
        out_alpha, out_h, out_c3);
}